// Round 4
// baseline (1189.055 us; speedup 1.0000x reference)
//
#include <hip/hip_runtime.h>
#include <hip/hip_bf16.h>
#include <math.h>

#define B_    2
#define S_    2048
#define H_    4096
#define NH_   32
#define HD_   128
#define MTOK_ (B_ * S_)     // 4096 tokens
#define QKVN_ (3 * H_)      // 12288

using bf16_t = __hip_bfloat16;
typedef __bf16 bf16x8 __attribute__((ext_vector_type(8)));
typedef unsigned short u16x8 __attribute__((ext_vector_type(8)));
typedef float f32x4 __attribute__((ext_vector_type(4)));

// async global->LDS, 16B per lane; LDS base must be wave-uniform
// (HW writes lane i at base + i*16B).
#define ASYNC_COPY16(g, l)                                                     \
  __builtin_amdgcn_global_load_lds(                                            \
      (__attribute__((address_space(1))) void*)(g),                            \
      (__attribute__((address_space(3))) void*)(l), 16, 0, 0)

static __device__ __forceinline__ f32x4 mfma16x16(bf16x8 a, bf16x8 b, f32x4 c) {
  return __builtin_amdgcn_mfma_f32_16x16x32_bf16(a, b, c, 0, 0, 0);
}

static __device__ __forceinline__ float bits_to_f(unsigned short v) {
  union { unsigned int u; float f; } cv;
  cv.u = ((unsigned int)v) << 16;
  return cv.f;
}

#define GBAR()                                                                 \
  do {                                                                         \
    __builtin_amdgcn_s_barrier();                                              \
    __builtin_amdgcn_sched_barrier(0);                                         \
  } while (0)

#define LGKM0()                                                                \
  do {                                                                         \
    asm volatile("s_waitcnt lgkmcnt(0)" ::: "memory");                         \
    __builtin_amdgcn_sched_barrier(0);                                         \
  } while (0)

// ---------------------------------------------------------------------------
// dtype probe: if the float inputs are fp32, random mantissa halves decode to
// huge bf16 values; if genuine bf16 (|x|<~0.2 here), all 64K u16s stay small.
// ---------------------------------------------------------------------------
__global__ void bh_detect(const unsigned short* __restrict__ p,
                          int* __restrict__ flag) {
  __shared__ float red[4];
  float m = 0.f;
  const int tid = threadIdx.x;
  for (int i = tid; i < 65536; i += 256) {
    const float f = fabsf(bits_to_f(p[i]));
    m = fmaxf(m, f);  // fmaxf(m, NaN) == m
  }
  for (int off = 1; off < 64; off <<= 1) m = fmaxf(m, __shfl_xor(m, off, 64));
  if ((tid & 63) == 0) red[tid >> 6] = m;
  __syncthreads();
  if (tid == 0) {
    const float mm = fmaxf(fmaxf(red[0], red[1]), fmaxf(red[2], red[3]));
    *flag = (mm > 1.0f) ? 1 : 0;  // 1 => inputs/outputs are fp32
  }
}

// ---------------------------------------------------------------------------
// one-shot dtype normalization: fp32 -> bf16 convert (or bf16 copy), so the
// GEMMs can always use the global_load_lds (async 16B) staging path.
// ---------------------------------------------------------------------------
__global__ __launch_bounds__(256)
void bh_convert(const void* __restrict__ src, bf16_t* __restrict__ dst,
                long n8, const int* __restrict__ flag) {
  const int isf = *flag;
  const long stride = (long)gridDim.x * 256;
  long i = (long)blockIdx.x * 256 + threadIdx.x;
  if (isf) {
    const f32x4* s = (const f32x4*)src;
    for (; i < n8; i += stride) {
      const f32x4 f0 = s[2 * i];
      const f32x4 f1 = s[2 * i + 1];
      bf16x8 o;
      o[0] = (__bf16)f0[0]; o[1] = (__bf16)f0[1];
      o[2] = (__bf16)f0[2]; o[3] = (__bf16)f0[3];
      o[4] = (__bf16)f1[0]; o[5] = (__bf16)f1[1];
      o[6] = (__bf16)f1[2]; o[7] = (__bf16)f1[3];
      *reinterpret_cast<bf16x8*>(dst + i * 8) = o;
    }
  } else {
    const u16x8* s = (const u16x8*)src;
    for (; i < n8; i += stride)
      reinterpret_cast<u16x8*>(dst)[i] = s[i];
  }
}

// fp32 staging: read 8 floats, convert, one ds_write_b128 (same LDS layout
// the async path produces).
static __device__ __forceinline__ void stage32(const float* __restrict__ g,
                                               bf16_t* __restrict__ l) {
  const f32x4 f0 = *reinterpret_cast<const f32x4*>(g);
  const f32x4 f1 = *reinterpret_cast<const f32x4*>(g + 4);
  bf16x8 o;
  o[0] = (__bf16)f0[0]; o[1] = (__bf16)f0[1];
  o[2] = (__bf16)f0[2]; o[3] = (__bf16)f0[3];
  o[4] = (__bf16)f1[0]; o[5] = (__bf16)f1[1];
  o[6] = (__bf16)f1[2]; o[7] = (__bf16)f1[3];
  *reinterpret_cast<bf16x8*>(l) = o;
}

// ---------------------------------------------------------------------------
// Fallback NT GEMM (128x128 tile, 2-barrier loop) for when the workspace is
// too small to pre-convert operands. Unchanged from the verified version.
// ---------------------------------------------------------------------------
template <int AMODE, int BMODE, int CMODE>
__global__ __launch_bounds__(256, 2)
void bh_gemm(const void* __restrict__ Ap, int lda,
             const void* __restrict__ Bp, int ldb,
             void* __restrict__ Cp, int ldc, int N, int K,
             const int* __restrict__ flag) {
  __shared__ bf16_t As[128 * 32];
  __shared__ bf16_t Bs[128 * 32];
  const int isf = *flag;
  const bool a_f32 = AMODE && isf;
  const bool b_f32 = BMODE && isf;

  const int tid = threadIdx.x, wave = tid >> 6, lane = tid & 63;
  const int lq = lane >> 4, lc = lane & 15;
  const int m0 = blockIdx.y * 128, n0 = blockIdx.x * 128;
  const int wm = (wave >> 1) * 64, wn = (wave & 1) * 64;

  f32x4 acc[4][4] = {};

  const int srow  = wave * 16 + (lane >> 2);
  const int skoff = (lane & 3) * 8;

  const bf16_t* a16 = (const bf16_t*)Ap;
  const float*  a32 = (const float*)Ap;
  const bf16_t* b16 = (const bf16_t*)Bp;
  const float*  b32 = (const float*)Bp;

  bf16_t* lA0u = As + wave * 512;
  bf16_t* lA1u = As + 2048 + wave * 512;
  bf16_t* lB0u = Bs + wave * 512;
  bf16_t* lB1u = Bs + 2048 + wave * 512;
  bf16_t* lA0p = lA0u + lane * 8;
  bf16_t* lA1p = lA1u + lane * 8;
  bf16_t* lB0p = lB0u + lane * 8;
  bf16_t* lB1p = lB1u + lane * 8;

  const int aoff = (wm + lc) * 32 + lq * 8;
  const int boff = (wn + lc) * 32 + lq * 8;

  for (int k = 0; k < K; k += 32) {
    if (a_f32) {
      stage32(a32 + (long)(m0 + srow) * lda + skoff + k, lA0p);
      stage32(a32 + (long)(m0 + srow + 64) * lda + skoff + k, lA1p);
    } else {
      ASYNC_COPY16(a16 + (long)(m0 + srow) * lda + skoff + k, lA0u);
      ASYNC_COPY16(a16 + (long)(m0 + srow + 64) * lda + skoff + k, lA1u);
    }
    if (b_f32) {
      stage32(b32 + (long)(n0 + srow) * ldb + skoff + k, lB0p);
      stage32(b32 + (long)(n0 + srow + 64) * ldb + skoff + k, lB1p);
    } else {
      ASYNC_COPY16(b16 + (long)(n0 + srow) * ldb + skoff + k, lB0u);
      ASYNC_COPY16(b16 + (long)(n0 + srow + 64) * ldb + skoff + k, lB1u);
    }
    __syncthreads();
    bf16x8 af[4], bfr[4];
#pragma unroll
    for (int i = 0; i < 4; ++i) {
      af[i]  = *reinterpret_cast<const bf16x8*>(&As[aoff + i * 512]);
      bfr[i] = *reinterpret_cast<const bf16x8*>(&Bs[boff + i * 512]);
    }
#pragma unroll
    for (int mi = 0; mi < 4; ++mi)
#pragma unroll
      for (int ni = 0; ni < 4; ++ni)
        acc[mi][ni] = mfma16x16(af[mi], bfr[ni], acc[mi][ni]);
    __syncthreads();
  }

  const bool c_f32 = CMODE && isf;
#pragma unroll
  for (int mi = 0; mi < 4; ++mi)
#pragma unroll
    for (int ni = 0; ni < 4; ++ni)
#pragma unroll
      for (int i = 0; i < 4; ++i) {
        const long row = m0 + wm + mi * 16 + lq * 4 + i;
        const long col = n0 + wn + ni * 16 + lc;
        const float v = acc[mi][ni][i];
        if (c_f32)
          ((float*)Cp)[row * ldc + col] = v;
        else
          ((bf16_t*)Cp)[row * ldc + col] = __float2bfloat16(v);
      }
}

// ---------------------------------------------------------------------------
// 256x256 8-phase bf16 NT GEMM (m201-style). BK=64, 8 waves, counted
// vmcnt(6), LDS XOR-swizzle chunk^=row&7 via pre-swizzled global source.
// XCD-aware bijective blockIdx swizzle (grid % 8 == 0 for both uses):
// each XCD gets a contiguous chunk of tiles, N-fastest, so its A panels
// stay L2-resident while B streams through L3 once chip-wide.
// ---------------------------------------------------------------------------
template <int CMODE>
__global__ __launch_bounds__(512, 2)
void bh_gemm2(const bf16_t* __restrict__ Ap, int lda,
              const bf16_t* __restrict__ Bp, int ldb,
              void* __restrict__ Cp, int ldc, int K,
              const int* __restrict__ flag) {
  __shared__ bf16_t As[2][2][128 * 64];
  __shared__ bf16_t Bs[2][2][128 * 64];
  const int isf = *flag;

  const int tid = threadIdx.x, wave = tid >> 6, lane = tid & 63;
  const int lq = lane >> 4, lc = lane & 15;
  const int wm2 = wave >> 2;
  const int wn4 = wave & 3;

  // XCD swizzle (nwg % 8 == 0): logical tile id = (orig%8)*chunk + orig/8
  const int nbx = gridDim.x;
  int bid = blockIdx.y * nbx + blockIdx.x;
  const int cpx = (nbx * gridDim.y) >> 3;
  bid = (bid & 7) * cpx + (bid >> 3);
  const int m0 = (bid / nbx) * 256, n0 = (bid % nbx) * 256;
  const int NT = K >> 6;

  const int srow = wave * 16 + (lane >> 3);
  const int gcol = ((lane & 7) ^ (lane >> 3)) * 8;
  const int lbase = wave * 1024;

  f32x4 acc[8][4] = {};
  bf16x8 aA[2][4];
  bf16x8 bB[2][2][2];

  auto stageA = [&](int tau, int h) {
    if (tau >= NT) return;
    const bf16_t* g = Ap + (long)(m0 + h * 128 + srow) * lda + tau * 64 + gcol;
    bf16_t* l = &As[tau & 1][h][lbase];
    ASYNC_COPY16(g, l);
    ASYNC_COPY16(g + (long)8 * lda, l + 512);
  };
  auto stageB = [&](int tau, int h) {
    if (tau >= NT) return;
    const bf16_t* g = Bp + (long)(n0 + h * 128 + srow) * ldb + tau * 64 + gcol;
    bf16_t* l = &Bs[tau & 1][h][lbase];
    ASYNC_COPY16(g, l);
    ASYNC_COPY16(g + (long)8 * ldb, l + 512);
  };
  auto ldA = [&](int buf, int h) {
#pragma unroll
    for (int ks = 0; ks < 2; ++ks)
#pragma unroll
      for (int f = 0; f < 4; ++f) {
        const int row = wm2 * 64 + f * 16 + lc;
        aA[ks][f] = *reinterpret_cast<const bf16x8*>(
            &As[buf][h][row * 64 + (((ks * 4 + lq) ^ (row & 7)) * 8)]);
      }
  };
  auto ldB = [&](int buf, int h, bf16x8 (&dst)[2][2]) {
#pragma unroll
    for (int ks = 0; ks < 2; ++ks)
#pragma unroll
      for (int g = 0; g < 2; ++g) {
        const int row = wn4 * 32 + g * 16 + lc;
        dst[ks][g] = *reinterpret_cast<const bf16x8*>(
            &Bs[buf][h][row * 64 + (((ks * 4 + lq) ^ (row & 7)) * 8)]);
      }
  };

#define MMA_QUAD(qm, qn)                                                       \
  do {                                                                         \
    __builtin_amdgcn_s_setprio(1);                                             \
    _Pragma("unroll") for (int f = 0; f < 4; ++f) {                            \
      _Pragma("unroll") for (int g = 0; g < 2; ++g) {                          \
        f32x4 c = acc[(qm) * 4 + f][(qn) * 2 + g];                             \
        c = mfma16x16(aA[0][f], bB[qn][0][g], c);                              \
        c = mfma16x16(aA[1][f], bB[qn][1][g], c);                              \
        acc[(qm) * 4 + f][(qn) * 2 + g] = c;                                   \
      }                                                                        \
    }                                                                          \
    __builtin_amdgcn_s_setprio(0);                                             \
  } while (0)

  stageA(0, 0); stageB(0, 0); stageB(0, 1); stageA(0, 1);
  stageA(1, 0); stageB(1, 0); stageB(1, 1);
  asm volatile("s_waitcnt vmcnt(6)" ::: "memory");
  GBAR();

  for (int T = 0; T < NT; ++T) {
    const int buf = T & 1;
    ldA(buf, 0);
    ldB(buf, 0, bB[0]);
    stageA(T + 1, 1);
    asm volatile("s_waitcnt lgkmcnt(8)" ::: "memory");
    GBAR();
    LGKM0();
    MMA_QUAD(0, 0);
    GBAR();
    ldB(buf, 1, bB[1]);
    stageA(T + 2, 0);
    GBAR();
    LGKM0();
    MMA_QUAD(0, 1);
    GBAR();
    ldA(buf, 1);
    stageB(T + 2, 0);
    GBAR();
    LGKM0();
    MMA_QUAD(1, 1);
    GBAR();
    stageB(T + 2, 1);
    if (T + 2 < NT)
      asm volatile("s_waitcnt vmcnt(6)" ::: "memory");
    else
      asm volatile("s_waitcnt vmcnt(0)" ::: "memory");
    GBAR();
    MMA_QUAD(1, 0);
    GBAR();
  }

  const bool c_f32 = CMODE && isf;
#pragma unroll
  for (int mi = 0; mi < 8; ++mi)
#pragma unroll
    for (int ni = 0; ni < 4; ++ni)
#pragma unroll
      for (int i = 0; i < 4; ++i) {
        const long row =
            m0 + (mi >> 2) * 128 + wm2 * 64 + (mi & 3) * 16 + lq * 4 + i;
        const long col =
            n0 + (ni >> 1) * 128 + wn4 * 32 + (ni & 1) * 16 + lc;
        const float v = acc[mi][ni][i];
        if (c_f32)
          ((float*)Cp)[row * ldc + col] = v;
        else
          ((bf16_t*)Cp)[row * ldc + col] = __float2bfloat16(v);
      }
}

// ---------------------------------------------------------------------------
// RoPE (neox half-split) in-place on Q and K regions of qkv (bf16).
// ---------------------------------------------------------------------------
__global__ void bh_rope(bf16_t* __restrict__ qkv, const int* __restrict__ pos) {
  const int idx = blockIdx.x * 256 + threadIdx.x;
  const int d = idx & 63;
  const int h = (idx >> 6) & (NH_ - 1);
  const int m = idx >> 11;
  if (m >= MTOK_) return;
  const float p = (float)pos[m];
  const float inv_freq = 1.0f / powf(10000.0f, (float)d * (1.0f / 64.0f));
  float sn, cs;
  sincosf(p * inv_freq, &sn, &cs);
  bf16_t* q  = qkv + (long)m * QKVN_ + h * HD_;
  bf16_t* kk = q + H_;
  const float q1 = __bfloat162float(q[d]);
  const float q2 = __bfloat162float(q[d + 64]);
  q[d]      = __float2bfloat16(q1 * cs - q2 * sn);
  q[d + 64] = __float2bfloat16(q2 * cs + q1 * sn);
  const float k1 = __bfloat162float(kk[d]);
  const float k2 = __bfloat162float(kk[d + 64]);
  kk[d]      = __float2bfloat16(k1 * cs - k2 * sn);
  kk[d + 64] = __float2bfloat16(k2 * cs + k1 * sn);
}

// ---------------------------------------------------------------------------
// V transpose: qkv V region [token][h*128+d] -> vt[b][h][d][token]
// ---------------------------------------------------------------------------
__global__ void bh_transpose_v(const bf16_t* __restrict__ qkv,
                               bf16_t* __restrict__ vt) {
  __shared__ unsigned short tile[128][65];
  const int t0 = blockIdx.x * 64;
  const int h  = blockIdx.y;
  const int b  = blockIdx.z;
  const int tid = threadIdx.x;
#pragma unroll
  for (int pass = 0; pass < 4; ++pass) {
    const int row = (tid >> 4) + pass * 16;
    const int dc  = (tid & 15) * 8;
    const u16x8 v = *reinterpret_cast<const u16x8*>(
        qkv + (long)(b * S_ + t0 + row) * QKVN_ + 2 * H_ + h * HD_ + dc);
#pragma unroll
    for (int j = 0; j < 8; ++j) tile[dc + j][row] = v[j];
  }
  __syncthreads();
#pragma unroll
  for (int pass = 0; pass < 4; ++pass) {
    const int d  = (tid >> 3) + pass * 32;
    const int tc = (tid & 7) * 8;
    u16x8 o;
#pragma unroll
    for (int j = 0; j < 8; ++j) o[j] = tile[d][tc + j];
    *reinterpret_cast<u16x8*>(
        vt + ((long)(b * NH_ + h) * HD_ + d) * S_ + t0 + tc) = o;
  }
}

// ---------------------------------------------------------------------------
// Causal flash attention, 256 Q-rows per block, 8 waves (wave w owns rows
// wrow..wrow+31), double-buffered K/V with counted per-wave vmcnt (each wave
// issues 4 async copies per tile -> vmcnt(4)). No __syncthreads in the loop
// (would drain vmcnt(0)). Per tile: stage(t+1,buf^1) | vmcnt(4) | s_barrier |
// QK^T | softmax (Ps rows wave-private, no barrier) | PV | s_barrier.
// Halves K/V DMA traffic vs the 128-row version and guarantees 8 waves/CU
// (LDS 96 KB -> 1 block/CU). Grid 1D longest-first: blocks 0..63 are qt=7
// (32 K-tiles), so critical-path blocks start at t=0; greedy longest-first
// balances CU makespan to ~mean. LDS XOR-swizzled (chunk ^= row&7, 16B
// units) on the global source of the async copies and on every ds_read.
// ---------------------------------------------------------------------------
__global__ __launch_bounds__(512)
void bh_flash(bf16_t* __restrict__ qkv, const bf16_t* __restrict__ vt) {
  __shared__ bf16_t Ks[2][64 * 128];   // [token][dim], dim-chunk ^= token&7
  __shared__ bf16_t Vs[2][128 * 64];   // [dim][token], token-chunk ^= dim&7
  __shared__ bf16_t Ps[256 * 64];      // [qrow][token], token-chunk ^= qrow&7
  const int idx = blockIdx.x;
  const int qt = (S_ / 256 - 1) - (idx >> 6);  // longest-first: 7..0
  const int bh = idx & 63;
  const int b  = bh >> 5;
  const int h  = bh & (NH_ - 1);
  const int tid = threadIdx.x, wave = tid >> 6, lane = tid & 63;
  const int lq = lane >> 4, lc = lane & 15;
  const int wrow = wave * 32;
  const float scale = 0.088388347648318447f;  // 1/sqrt(128)

  bf16x8 qf[2][4];
#pragma unroll
  for (int mt = 0; mt < 2; ++mt) {
    const bf16_t* qp =
        qkv + (long)(b * S_ + qt * 256 + wrow + mt * 16 + lc) * QKVN_ +
        h * HD_ + lq * 8;
#pragma unroll
    for (int ks = 0; ks < 4; ++ks)
      qf[mt][ks] = *reinterpret_cast<const bf16x8*>(qp + ks * 32);
  }

  f32x4 o_acc[2][8] = {};
  float m_st[2][4], l_st[2][4];
#pragma unroll
  for (int mt = 0; mt < 2; ++mt)
#pragma unroll
    for (int i = 0; i < 4; ++i) { m_st[mt][i] = -1e30f; l_st[mt][i] = 0.f; }

  // stage K/V tile kt into buffer bsel (4 async copies per wave, 8 waves)
  auto stage = [&](int kt, int bsel) {
    const int t0 = kt * 64;
#pragma unroll
    for (int j = 0; j < 2; ++j) {
      const int p = wave * 2 + j;
      const int trow = p * 4 + (lane >> 4);
      const int kcs  = ((lane & 15) ^ (trow & 7)) * 8;
      ASYNC_COPY16(qkv + (long)(b * S_ + t0 + trow) * QKVN_ + H_ + h * HD_ + kcs,
                   &Ks[bsel][p * 512]);
      const int vrow = p * 8 + (lane >> 3);
      const int tcs  = ((lane & 7) ^ (lane >> 3)) * 8;   // vrow&7 == lane>>3
      ASYNC_COPY16(vt + ((long)(b * NH_ + h) * HD_ + vrow) * S_ + t0 + tcs,
                   &Vs[bsel][p * 512]);
    }
  };

  const int ktiles = 4 * qt + 4;
  stage(0, 0);

  for (int kt = 0; kt < ktiles; ++kt) {
    const int cur = kt & 1;
    if (kt + 1 < ktiles) {
      stage(kt + 1, cur ^ 1);
      asm volatile("s_waitcnt vmcnt(4)" ::: "memory");
    } else {
      asm volatile("s_waitcnt vmcnt(0)" ::: "memory");
    }
    GBAR();

    const int t0 = kt * 64;
    f32x4 sa[2][4] = {};
    __builtin_amdgcn_s_setprio(1);
#pragma unroll
    for (int ks = 0; ks < 4; ++ks) {
      bf16x8 bb[4];
#pragma unroll
      for (int nt = 0; nt < 4; ++nt)
        bb[nt] = *reinterpret_cast<const bf16x8*>(
            &Ks[cur][(nt * 16 + lc) * 128 +
                     ((ks * 32 + lq * 8) ^ ((lc & 7) << 3))]);
#pragma unroll
      for (int mt = 0; mt < 2; ++mt)
#pragma unroll
        for (int nt = 0; nt < 4; ++nt)
          sa[mt][nt] = mfma16x16(qf[mt][ks], bb[nt], sa[mt][nt]);
    }
    __builtin_amdgcn_s_setprio(0);

#pragma unroll
    for (int mt = 0; mt < 2; ++mt) {
#pragma unroll
      for (int i = 0; i < 4; ++i) {
        const int qg = qt * 256 + wrow + mt * 16 + lq * 4 + i;
        float sv[4];
        float mloc = -1e30f;
#pragma unroll
        for (int nt = 0; nt < 4; ++nt) {
          float v = sa[mt][nt][i] * scale;
          if (t0 + nt * 16 + lc > qg) v = -1e30f;
          sv[nt] = v;
          mloc = fmaxf(mloc, v);
        }
#pragma unroll
        for (int off = 1; off < 16; off <<= 1)
          mloc = fmaxf(mloc, __shfl_xor(mloc, off, 64));
        const float mnew = fmaxf(m_st[mt][i], mloc);
        const float alpha = __expf(m_st[mt][i] - mnew);
        float rsum = 0.f;
        const int psw = ((lq * 4 + i) & 7) << 3;   // row&7 of the Ps row
#pragma unroll
        for (int nt = 0; nt < 4; ++nt) {
          const float pp = __expf(sv[nt] - mnew);
          rsum += pp;
          Ps[(wrow + mt * 16 + lq * 4 + i) * 64 + ((nt * 16 + lc) ^ psw)] =
              __float2bfloat16(pp);
        }
#pragma unroll
        for (int off = 1; off < 16; off <<= 1)
          rsum += __shfl_xor(rsum, off, 64);
        l_st[mt][i] = l_st[mt][i] * alpha + rsum;
        m_st[mt][i] = mnew;
#pragma unroll
        for (int nt = 0; nt < 8; ++nt) o_acc[mt][nt][i] *= alpha;
      }
    }
    // no barrier: Ps rows written/read by the same wave only

    __builtin_amdgcn_s_setprio(1);
#pragma unroll
    for (int ks = 0; ks < 2; ++ks) {
      bf16x8 pa[2];
#pragma unroll
      for (int mt = 0; mt < 2; ++mt)
        pa[mt] = *reinterpret_cast<const bf16x8*>(
            &Ps[(wrow + mt * 16 + lc) * 64 +
                ((ks * 32 + lq * 8) ^ ((lc & 7) << 3))]);
#pragma unroll
      for (int nt = 0; nt < 8; ++nt) {
        const bf16x8 vb = *reinterpret_cast<const bf16x8*>(
            &Vs[cur][(nt * 16 + lc) * 64 +
                     ((ks * 32 + lq * 8) ^ ((lc & 7) << 3))]);
#pragma unroll
        for (int mt = 0; mt < 2; ++mt)
          o_acc[mt][nt] = mfma16x16(pa[mt], vb, o_acc[mt][nt]);
      }
    }
    __builtin_amdgcn_s_setprio(0);
    GBAR();   // this tile's reads done before next tile's DMA into buf^1
  }

  // write attention output into the Q region of qkv
#pragma unroll
  for (int mt = 0; mt < 2; ++mt)
#pragma unroll
    for (int i = 0; i < 4; ++i) {
      const float inv_l = 1.0f / l_st[mt][i];
      bf16_t* op =
          qkv + (long)(b * S_ + qt * 256 + wrow + mt * 16 + lq * 4 + i) * QKVN_ +
          h * HD_ + lc;
#pragma unroll
      for (int nt = 0; nt < 8; ++nt)
        op[nt * 16] = __float2bfloat16(o_acc[mt][nt][i] * inv_l);
    }
}

// ---------------------------------------------------------------------------
extern "C" void kernel_launch(void* const* d_in, const int* in_sizes, int n_in,
                              void* d_out, int out_size, void* d_ws,
                              size_t ws_size, hipStream_t stream) {
  const int* pos = (const int*)d_in[3];

  char* ws = (char*)d_ws;
  bf16_t* qkv  = (bf16_t*)ws;                                   // 100.66 MB
  const size_t QKV_B = (size_t)MTOK_ * QKVN_ * 2;
  int*    flag = (int*)(ws + QKV_B);
  bf16_t* vt   = (bf16_t*)d_out;  // scratch before final out is written

  // tiered bf16 conversion scratch (enables global_load_lds in the GEMMs)
  const size_t off  = QKV_B + 512;
  const size_t WP_B = (size_t)QKVN_ * H_ * 2;   // 100.66 MB
  const size_t WO_B = (size_t)H_ * H_ * 2;      //  33.55 MB
  const size_t A_B  = (size_t)MTOK_ * H_ * 2;   //  33.55 MB
  const bool cvtWP = ws_size >= off + WP_B;
  const bool cvtWO = ws_size >= off + WP_B + WO_B;
  const bool cvtA  = ws_size >= off + WP_B + WO_B + A_B;
  bf16_t* wpb = (bf16_t*)(ws + off);
  bf16_t* wob = (bf16_t*)(ws + off + WP_B);
  bf16_t* abf = (bf16_t*)(ws + off + WP_B + WO_B);

  bh_detect<<<dim3(1), dim3(256), 0, stream>>>(
      (const unsigned short*)d_in[1], flag);

  if (cvtWP)
    bh_convert<<<dim3(2048), dim3(256), 0, stream>>>(
        d_in[1], wpb, (long)QKVN_ * H_ / 8, flag);
  if (cvtWO)
    bh_convert<<<dim3(2048), dim3(256), 0, stream>>>(
        d_in[2], wob, (long)H_ * H_ / 8, flag);
  if (cvtA)
    bh_convert<<<dim3(2048), dim3(256), 0, stream>>>(
        d_in[0], abf, (long)MTOK_ * H_ / 8, flag);

  if (cvtA)
    bh_gemm2<0><<<dim3(QKVN_ / 256, MTOK_ / 256), dim3(512), 0, stream>>>(
        abf, H_, wpb, H_, qkv, QKVN_, H_, flag);
  else if (cvtWP)
    bh_gemm<1, 0, 0><<<dim3(QKVN_ / 128, MTOK_ / 128), dim3(256), 0, stream>>>(
        d_in[0], H_, wpb, H_, qkv, QKVN_, QKVN_, H_, flag);
  else
    bh_gemm<1, 1, 0><<<dim3(QKVN_ / 128, MTOK_ / 128), dim3(256), 0, stream>>>(
        d_in[0], H_, d_in[1], H_, qkv, QKVN_, QKVN_, H_, flag);

  bh_rope<<<dim3((MTOK_ * NH_ * 64) / 256), dim3(256), 0, stream>>>(qkv, pos);
  bh_transpose_v<<<dim3(S_ / 64, NH_, B_), dim3(256), 0, stream>>>(qkv, vt);
  bh_flash<<<dim3((S_ / 256) * NH_ * B_), dim3(512), 0, stream>>>(qkv, vt);

  if (cvtWO)
    bh_gemm2<1><<<dim3(H_ / 256, MTOK_ / 256), dim3(512), 0, stream>>>(
        qkv, QKVN_, wob, H_, d_out, H_, H_, flag);
  else
    bh_gemm<0, 1, 1><<<dim3(H_ / 128, MTOK_ / 128), dim3(256), 0, stream>>>(
        qkv, QKVN_, d_in[2], H_, d_out, H_, H_, H_, flag);
}

// Round 5
// 1146.020 us; speedup vs baseline: 1.0376x; 1.0376x over previous
//
#include <hip/hip_runtime.h>
#include <hip/hip_bf16.h>
#include <math.h>

#define B_    2
#define S_    2048
#define H_    4096
#define NH_   32
#define HD_   128
#define MTOK_ (B_ * S_)     // 4096 tokens
#define QKVN_ (3 * H_)      // 12288

using bf16_t = __hip_bfloat16;
typedef __bf16 bf16x8 __attribute__((ext_vector_type(8)));
typedef unsigned short u16x8 __attribute__((ext_vector_type(8)));
typedef float f32x4 __attribute__((ext_vector_type(4)));

// async global->LDS, 16B per lane; LDS base must be wave-uniform
// (HW writes lane i at base + i*16B).
#define ASYNC_COPY16(g, l)                                                     \
  __builtin_amdgcn_global_load_lds(                                            \
      (__attribute__((address_space(1))) void*)(g),                            \
      (__attribute__((address_space(3))) void*)(l), 16, 0, 0)

static __device__ __forceinline__ f32x4 mfma16x16(bf16x8 a, bf16x8 b, f32x4 c) {
  return __builtin_amdgcn_mfma_f32_16x16x32_bf16(a, b, c, 0, 0, 0);
}

static __device__ __forceinline__ float bits_to_f(unsigned short v) {
  union { unsigned int u; float f; } cv;
  cv.u = ((unsigned int)v) << 16;
  return cv.f;
}

// raw v_exp_f32 (2^x). Non-volatile: pure, lets the scheduler place it.
static __device__ __forceinline__ float exp2_hw(float x) {
  float r;
  asm("v_exp_f32 %0, %1" : "=v"(r) : "v"(x));
  return r;
}

#define GBAR()                                                                 \
  do {                                                                         \
    __builtin_amdgcn_s_barrier();                                              \
    __builtin_amdgcn_sched_barrier(0);                                         \
  } while (0)

#define LGKM0()                                                                \
  do {                                                                         \
    asm volatile("s_waitcnt lgkmcnt(0)" ::: "memory");                         \
    __builtin_amdgcn_sched_barrier(0);                                         \
  } while (0)

// ---------------------------------------------------------------------------
// dtype probe: if the float inputs are fp32, random mantissa halves decode to
// huge bf16 values; if genuine bf16 (|x|<~0.2 here), all 64K u16s stay small.
// ---------------------------------------------------------------------------
__global__ void bh_detect(const unsigned short* __restrict__ p,
                          int* __restrict__ flag) {
  __shared__ float red[4];
  float m = 0.f;
  const int tid = threadIdx.x;
  for (int i = tid; i < 65536; i += 256) {
    const float f = fabsf(bits_to_f(p[i]));
    m = fmaxf(m, f);  // fmaxf(m, NaN) == m
  }
  for (int off = 1; off < 64; off <<= 1) m = fmaxf(m, __shfl_xor(m, off, 64));
  if ((tid & 63) == 0) red[tid >> 6] = m;
  __syncthreads();
  if (tid == 0) {
    const float mm = fmaxf(fmaxf(red[0], red[1]), fmaxf(red[2], red[3]));
    *flag = (mm > 1.0f) ? 1 : 0;  // 1 => inputs/outputs are fp32
  }
}

// ---------------------------------------------------------------------------
// one-shot dtype normalization: fp32 -> bf16 convert (or bf16 copy), so the
// GEMMs can always use the global_load_lds (async 16B) staging path.
// ---------------------------------------------------------------------------
__global__ __launch_bounds__(256)
void bh_convert(const void* __restrict__ src, bf16_t* __restrict__ dst,
                long n8, const int* __restrict__ flag) {
  const int isf = *flag;
  const long stride = (long)gridDim.x * 256;
  long i = (long)blockIdx.x * 256 + threadIdx.x;
  if (isf) {
    const f32x4* s = (const f32x4*)src;
    for (; i < n8; i += stride) {
      const f32x4 f0 = s[2 * i];
      const f32x4 f1 = s[2 * i + 1];
      bf16x8 o;
      o[0] = (__bf16)f0[0]; o[1] = (__bf16)f0[1];
      o[2] = (__bf16)f0[2]; o[3] = (__bf16)f0[3];
      o[4] = (__bf16)f1[0]; o[5] = (__bf16)f1[1];
      o[6] = (__bf16)f1[2]; o[7] = (__bf16)f1[3];
      *reinterpret_cast<bf16x8*>(dst + i * 8) = o;
    }
  } else {
    const u16x8* s = (const u16x8*)src;
    for (; i < n8; i += stride)
      reinterpret_cast<u16x8*>(dst)[i] = s[i];
  }
}

// fp32 staging: read 8 floats, convert, one ds_write_b128 (same LDS layout
// the async path produces).
static __device__ __forceinline__ void stage32(const float* __restrict__ g,
                                               bf16_t* __restrict__ l) {
  const f32x4 f0 = *reinterpret_cast<const f32x4*>(g);
  const f32x4 f1 = *reinterpret_cast<const f32x4*>(g + 4);
  bf16x8 o;
  o[0] = (__bf16)f0[0]; o[1] = (__bf16)f0[1];
  o[2] = (__bf16)f0[2]; o[3] = (__bf16)f0[3];
  o[4] = (__bf16)f1[0]; o[5] = (__bf16)f1[1];
  o[6] = (__bf16)f1[2]; o[7] = (__bf16)f1[3];
  *reinterpret_cast<bf16x8*>(l) = o;
}

// ---------------------------------------------------------------------------
// Fallback NT GEMM (128x128 tile, 2-barrier loop) for when the workspace is
// too small to pre-convert operands. Unchanged from the verified version.
// ---------------------------------------------------------------------------
template <int AMODE, int BMODE, int CMODE>
__global__ __launch_bounds__(256, 2)
void bh_gemm(const void* __restrict__ Ap, int lda,
             const void* __restrict__ Bp, int ldb,
             void* __restrict__ Cp, int ldc, int N, int K,
             const int* __restrict__ flag) {
  __shared__ bf16_t As[128 * 32];
  __shared__ bf16_t Bs[128 * 32];
  const int isf = *flag;
  const bool a_f32 = AMODE && isf;
  const bool b_f32 = BMODE && isf;

  const int tid = threadIdx.x, wave = tid >> 6, lane = tid & 63;
  const int lq = lane >> 4, lc = lane & 15;
  const int m0 = blockIdx.y * 128, n0 = blockIdx.x * 128;
  const int wm = (wave >> 1) * 64, wn = (wave & 1) * 64;

  f32x4 acc[4][4] = {};

  const int srow  = wave * 16 + (lane >> 2);
  const int skoff = (lane & 3) * 8;

  const bf16_t* a16 = (const bf16_t*)Ap;
  const float*  a32 = (const float*)Ap;
  const bf16_t* b16 = (const bf16_t*)Bp;
  const float*  b32 = (const float*)Bp;

  bf16_t* lA0u = As + wave * 512;
  bf16_t* lA1u = As + 2048 + wave * 512;
  bf16_t* lB0u = Bs + wave * 512;
  bf16_t* lB1u = Bs + 2048 + wave * 512;
  bf16_t* lA0p = lA0u + lane * 8;
  bf16_t* lA1p = lA1u + lane * 8;
  bf16_t* lB0p = lB0u + lane * 8;
  bf16_t* lB1p = lB1u + lane * 8;

  const int aoff = (wm + lc) * 32 + lq * 8;
  const int boff = (wn + lc) * 32 + lq * 8;

  for (int k = 0; k < K; k += 32) {
    if (a_f32) {
      stage32(a32 + (long)(m0 + srow) * lda + skoff + k, lA0p);
      stage32(a32 + (long)(m0 + srow + 64) * lda + skoff + k, lA1p);
    } else {
      ASYNC_COPY16(a16 + (long)(m0 + srow) * lda + skoff + k, lA0u);
      ASYNC_COPY16(a16 + (long)(m0 + srow + 64) * lda + skoff + k, lA1u);
    }
    if (b_f32) {
      stage32(b32 + (long)(n0 + srow) * ldb + skoff + k, lB0p);
      stage32(b32 + (long)(n0 + srow + 64) * ldb + skoff + k, lB1p);
    } else {
      ASYNC_COPY16(b16 + (long)(n0 + srow) * ldb + skoff + k, lB0u);
      ASYNC_COPY16(b16 + (long)(n0 + srow + 64) * ldb + skoff + k, lB1u);
    }
    __syncthreads();
    bf16x8 af[4], bfr[4];
#pragma unroll
    for (int i = 0; i < 4; ++i) {
      af[i]  = *reinterpret_cast<const bf16x8*>(&As[aoff + i * 512]);
      bfr[i] = *reinterpret_cast<const bf16x8*>(&Bs[boff + i * 512]);
    }
#pragma unroll
    for (int mi = 0; mi < 4; ++mi)
#pragma unroll
      for (int ni = 0; ni < 4; ++ni)
        acc[mi][ni] = mfma16x16(af[mi], bfr[ni], acc[mi][ni]);
    __syncthreads();
  }

  const bool c_f32 = CMODE && isf;
#pragma unroll
  for (int mi = 0; mi < 4; ++mi)
#pragma unroll
    for (int ni = 0; ni < 4; ++ni)
#pragma unroll
      for (int i = 0; i < 4; ++i) {
        const long row = m0 + wm + mi * 16 + lq * 4 + i;
        const long col = n0 + wn + ni * 16 + lc;
        const float v = acc[mi][ni][i];
        if (c_f32)
          ((float*)Cp)[row * ldc + col] = v;
        else
          ((bf16_t*)Cp)[row * ldc + col] = __float2bfloat16(v);
      }
}

// ---------------------------------------------------------------------------
// 256x256 8-phase bf16 NT GEMM (m201-style). BK=64, 8 waves, counted
// vmcnt(6), LDS XOR-swizzle chunk^=row&7 via pre-swizzled global source.
// NO XCD swizzle: operands are L3-fit here (134 MB), and R4's A/B showed the
// chunked swizzle desynchronizes the XCD sweeps over B -> FETCH 295->825 MB,
// dur +18 us. Natural row-major block order keeps ~5 rows x all cols
// co-resident, which is the better L3 reuse pattern at this shape.
// ---------------------------------------------------------------------------
template <int CMODE>
__global__ __launch_bounds__(512, 2)
void bh_gemm2(const bf16_t* __restrict__ Ap, int lda,
              const bf16_t* __restrict__ Bp, int ldb,
              void* __restrict__ Cp, int ldc, int K,
              const int* __restrict__ flag) {
  __shared__ bf16_t As[2][2][128 * 64];
  __shared__ bf16_t Bs[2][2][128 * 64];
  const int isf = *flag;

  const int tid = threadIdx.x, wave = tid >> 6, lane = tid & 63;
  const int lq = lane >> 4, lc = lane & 15;
  const int wm2 = wave >> 2;
  const int wn4 = wave & 3;
  const int m0 = blockIdx.y * 256, n0 = blockIdx.x * 256;
  const int NT = K >> 6;

  const int srow = wave * 16 + (lane >> 3);
  const int gcol = ((lane & 7) ^ (lane >> 3)) * 8;
  const int lbase = wave * 1024;

  f32x4 acc[8][4] = {};
  bf16x8 aA[2][4];
  bf16x8 bB[2][2][2];

  auto stageA = [&](int tau, int h) {
    if (tau >= NT) return;
    const bf16_t* g = Ap + (long)(m0 + h * 128 + srow) * lda + tau * 64 + gcol;
    bf16_t* l = &As[tau & 1][h][lbase];
    ASYNC_COPY16(g, l);
    ASYNC_COPY16(g + (long)8 * lda, l + 512);
  };
  auto stageB = [&](int tau, int h) {
    if (tau >= NT) return;
    const bf16_t* g = Bp + (long)(n0 + h * 128 + srow) * ldb + tau * 64 + gcol;
    bf16_t* l = &Bs[tau & 1][h][lbase];
    ASYNC_COPY16(g, l);
    ASYNC_COPY16(g + (long)8 * ldb, l + 512);
  };
  auto ldA = [&](int buf, int h) {
#pragma unroll
    for (int ks = 0; ks < 2; ++ks)
#pragma unroll
      for (int f = 0; f < 4; ++f) {
        const int row = wm2 * 64 + f * 16 + lc;
        aA[ks][f] = *reinterpret_cast<const bf16x8*>(
            &As[buf][h][row * 64 + (((ks * 4 + lq) ^ (row & 7)) * 8)]);
      }
  };
  auto ldB = [&](int buf, int h, bf16x8 (&dst)[2][2]) {
#pragma unroll
    for (int ks = 0; ks < 2; ++ks)
#pragma unroll
      for (int g = 0; g < 2; ++g) {
        const int row = wn4 * 32 + g * 16 + lc;
        dst[ks][g] = *reinterpret_cast<const bf16x8*>(
            &Bs[buf][h][row * 64 + (((ks * 4 + lq) ^ (row & 7)) * 8)]);
      }
  };

#define MMA_QUAD(qm, qn)                                                       \
  do {                                                                         \
    __builtin_amdgcn_s_setprio(1);                                             \
    _Pragma("unroll") for (int f = 0; f < 4; ++f) {                            \
      _Pragma("unroll") for (int g = 0; g < 2; ++g) {                          \
        f32x4 c = acc[(qm) * 4 + f][(qn) * 2 + g];                             \
        c = mfma16x16(aA[0][f], bB[qn][0][g], c);                              \
        c = mfma16x16(aA[1][f], bB[qn][1][g], c);                              \
        acc[(qm) * 4 + f][(qn) * 2 + g] = c;                                   \
      }                                                                        \
    }                                                                          \
    __builtin_amdgcn_s_setprio(0);                                             \
  } while (0)

  stageA(0, 0); stageB(0, 0); stageB(0, 1); stageA(0, 1);
  stageA(1, 0); stageB(1, 0); stageB(1, 1);
  asm volatile("s_waitcnt vmcnt(6)" ::: "memory");
  GBAR();

  for (int T = 0; T < NT; ++T) {
    const int buf = T & 1;
    ldA(buf, 0);
    ldB(buf, 0, bB[0]);
    stageA(T + 1, 1);
    asm volatile("s_waitcnt lgkmcnt(8)" ::: "memory");
    GBAR();
    LGKM0();
    MMA_QUAD(0, 0);
    GBAR();
    ldB(buf, 1, bB[1]);
    stageA(T + 2, 0);
    GBAR();
    LGKM0();
    MMA_QUAD(0, 1);
    GBAR();
    ldA(buf, 1);
    stageB(T + 2, 0);
    GBAR();
    LGKM0();
    MMA_QUAD(1, 1);
    GBAR();
    stageB(T + 2, 1);
    if (T + 2 < NT)
      asm volatile("s_waitcnt vmcnt(6)" ::: "memory");
    else
      asm volatile("s_waitcnt vmcnt(0)" ::: "memory");
    GBAR();
    MMA_QUAD(1, 0);
    GBAR();
  }

  const bool c_f32 = CMODE && isf;
#pragma unroll
  for (int mi = 0; mi < 8; ++mi)
#pragma unroll
    for (int ni = 0; ni < 4; ++ni)
#pragma unroll
      for (int i = 0; i < 4; ++i) {
        const long row =
            m0 + (mi >> 2) * 128 + wm2 * 64 + (mi & 3) * 16 + lq * 4 + i;
        const long col =
            n0 + (ni >> 1) * 128 + wn4 * 32 + (ni & 1) * 16 + lc;
        const float v = acc[mi][ni][i];
        if (c_f32)
          ((float*)Cp)[row * ldc + col] = v;
        else
          ((bf16_t*)Cp)[row * ldc + col] = __float2bfloat16(v);
      }
}

// ---------------------------------------------------------------------------
// RoPE (neox half-split) in-place on Q and K regions of qkv (bf16).
// ---------------------------------------------------------------------------
__global__ void bh_rope(bf16_t* __restrict__ qkv, const int* __restrict__ pos) {
  const int idx = blockIdx.x * 256 + threadIdx.x;
  const int d = idx & 63;
  const int h = (idx >> 6) & (NH_ - 1);
  const int m = idx >> 11;
  if (m >= MTOK_) return;
  const float p = (float)pos[m];
  const float inv_freq = 1.0f / powf(10000.0f, (float)d * (1.0f / 64.0f));
  float sn, cs;
  sincosf(p * inv_freq, &sn, &cs);
  bf16_t* q  = qkv + (long)m * QKVN_ + h * HD_;
  bf16_t* kk = q + H_;
  const float q1 = __bfloat162float(q[d]);
  const float q2 = __bfloat162float(q[d + 64]);
  q[d]      = __float2bfloat16(q1 * cs - q2 * sn);
  q[d + 64] = __float2bfloat16(q2 * cs + q1 * sn);
  const float k1 = __bfloat162float(kk[d]);
  const float k2 = __bfloat162float(kk[d + 64]);
  kk[d]      = __float2bfloat16(k1 * cs - k2 * sn);
  kk[d + 64] = __float2bfloat16(k2 * cs + k1 * sn);
}

// ---------------------------------------------------------------------------
// V transpose: qkv V region [token][h*128+d] -> vt[b][h][d][token]
// ---------------------------------------------------------------------------
__global__ void bh_transpose_v(const bf16_t* __restrict__ qkv,
                               bf16_t* __restrict__ vt) {
  __shared__ unsigned short tile[128][65];
  const int t0 = blockIdx.x * 64;
  const int h  = blockIdx.y;
  const int b  = blockIdx.z;
  const int tid = threadIdx.x;
#pragma unroll
  for (int pass = 0; pass < 4; ++pass) {
    const int row = (tid >> 4) + pass * 16;
    const int dc  = (tid & 15) * 8;
    const u16x8 v = *reinterpret_cast<const u16x8*>(
        qkv + (long)(b * S_ + t0 + row) * QKVN_ + 2 * H_ + h * HD_ + dc);
#pragma unroll
    for (int j = 0; j < 8; ++j) tile[dc + j][row] = v[j];
  }
  __syncthreads();
#pragma unroll
  for (int pass = 0; pass < 4; ++pass) {
    const int d  = (tid >> 3) + pass * 32;
    const int tc = (tid & 7) * 8;
    u16x8 o;
#pragma unroll
    for (int j = 0; j < 8; ++j) o[j] = tile[d][tc + j];
    *reinterpret_cast<u16x8*>(
        vt + ((long)(b * NH_ + h) * HD_ + d) * S_ + t0 + tc) = o;
  }
}

// ---------------------------------------------------------------------------
// Causal flash attention, 256 Q-rows / 8 waves per block, double-buffered K/V
// with counted per-wave vmcnt(4). Softmax in log2 domain (scale2 = log2e /
// sqrt(128), raw v_exp_f32), T13 defer-max (skip rescale while the row max
// grows <= 8 in log2 units; p bounded by 2^8), and per-lane partial l
// (linear in p) reduced across the 16-lane row group ONCE at the end instead
// of every tile. These cut the per-tile serial VALU chain (the flash
// critical path) by ~30-40%. Sync structure unchanged from the verified R3/R4
// version: stage(t+1,buf^1) | vmcnt(4) | s_barrier | QK^T | softmax (Ps
// wave-private) | PV | s_barrier. Grid 1D longest-first.
// ---------------------------------------------------------------------------
__global__ __launch_bounds__(512)
void bh_flash(bf16_t* __restrict__ qkv, const bf16_t* __restrict__ vt) {
  __shared__ bf16_t Ks[2][64 * 128];   // [token][dim], dim-chunk ^= token&7
  __shared__ bf16_t Vs[2][128 * 64];   // [dim][token], token-chunk ^= dim&7
  __shared__ bf16_t Ps[256 * 64];      // [qrow][token], token-chunk ^= qrow&7
  const int idx = blockIdx.x;
  const int qt = (S_ / 256 - 1) - (idx >> 6);  // longest-first: 7..0
  const int bh = idx & 63;
  const int b  = bh >> 5;
  const int h  = bh & (NH_ - 1);
  const int tid = threadIdx.x, wave = tid >> 6, lane = tid & 63;
  const int lq = lane >> 4, lc = lane & 15;
  const int wrow = wave * 32;
  const float scale2 = 0.12751744f;  // log2(e) / sqrt(128)

  bf16x8 qf[2][4];
#pragma unroll
  for (int mt = 0; mt < 2; ++mt) {
    const bf16_t* qp =
        qkv + (long)(b * S_ + qt * 256 + wrow + mt * 16 + lc) * QKVN_ +
        h * HD_ + lq * 8;
#pragma unroll
    for (int ks = 0; ks < 4; ++ks)
      qf[mt][ks] = *reinterpret_cast<const bf16x8*>(qp + ks * 32);
  }

  f32x4 o_acc[2][8] = {};
  float m_st[2][4], l_st[2][4];
#pragma unroll
  for (int mt = 0; mt < 2; ++mt)
#pragma unroll
    for (int i = 0; i < 4; ++i) { m_st[mt][i] = -1e30f; l_st[mt][i] = 0.f; }

  // stage K/V tile kt into buffer bsel (4 async copies per wave, 8 waves)
  auto stage = [&](int kt, int bsel) {
    const int t0 = kt * 64;
#pragma unroll
    for (int j = 0; j < 2; ++j) {
      const int p = wave * 2 + j;
      const int trow = p * 4 + (lane >> 4);
      const int kcs  = ((lane & 15) ^ (trow & 7)) * 8;
      ASYNC_COPY16(qkv + (long)(b * S_ + t0 + trow) * QKVN_ + H_ + h * HD_ + kcs,
                   &Ks[bsel][p * 512]);
      const int vrow = p * 8 + (lane >> 3);
      const int tcs  = ((lane & 7) ^ (lane >> 3)) * 8;   // vrow&7 == lane>>3
      ASYNC_COPY16(vt + ((long)(b * NH_ + h) * HD_ + vrow) * S_ + t0 + tcs,
                   &Vs[bsel][p * 512]);
    }
  };

  const int ktiles = 4 * qt + 4;
  stage(0, 0);

  for (int kt = 0; kt < ktiles; ++kt) {
    const int cur = kt & 1;
    if (kt + 1 < ktiles) {
      stage(kt + 1, cur ^ 1);
      asm volatile("s_waitcnt vmcnt(4)" ::: "memory");
    } else {
      asm volatile("s_waitcnt vmcnt(0)" ::: "memory");
    }
    GBAR();

    const int t0 = kt * 64;
    f32x4 sa[2][4] = {};
    __builtin_amdgcn_s_setprio(1);
#pragma unroll
    for (int ks = 0; ks < 4; ++ks) {
      bf16x8 bb[4];
#pragma unroll
      for (int nt = 0; nt < 4; ++nt)
        bb[nt] = *reinterpret_cast<const bf16x8*>(
            &Ks[cur][(nt * 16 + lc) * 128 +
                     ((ks * 32 + lq * 8) ^ ((lc & 7) << 3))]);
#pragma unroll
      for (int mt = 0; mt < 2; ++mt)
#pragma unroll
        for (int nt = 0; nt < 4; ++nt)
          sa[mt][nt] = mfma16x16(qf[mt][ks], bb[nt], sa[mt][nt]);
    }
    __builtin_amdgcn_s_setprio(0);

#pragma unroll
    for (int mt = 0; mt < 2; ++mt) {
#pragma unroll
      for (int i = 0; i < 4; ++i) {
        const int qg = qt * 256 + wrow + mt * 16 + lq * 4 + i;
        float sv[4];
        float mloc = -1e30f;
#pragma unroll
        for (int nt = 0; nt < 4; ++nt) {
          float v = sa[mt][nt][i] * scale2;
          if (t0 + nt * 16 + lc > qg) v = -1e30f;
          sv[nt] = v;
          mloc = fmaxf(mloc, v);
        }
#pragma unroll
        for (int off = 1; off < 16; off <<= 1)
          mloc = fmaxf(mloc, __shfl_xor(mloc, off, 64));
        // T13 defer-max: rescale only when the row max grew > 8 (log2 units).
        // p is then bounded by 2^8 = 256 -- fine for bf16 P and fp32 l.
        if (!__all(mloc - m_st[mt][i] <= 8.0f)) {
          const float mnew = fmaxf(m_st[mt][i], mloc);
          const float alpha = exp2_hw(m_st[mt][i] - mnew);
          l_st[mt][i] *= alpha;
#pragma unroll
          for (int nt = 0; nt < 8; ++nt) o_acc[mt][nt][i] *= alpha;
          m_st[mt][i] = mnew;
        }
        const float mcur = m_st[mt][i];
        float rsum = 0.f;
        const int psw = ((lq * 4 + i) & 7) << 3;   // row&7 of the Ps row
#pragma unroll
        for (int nt = 0; nt < 4; ++nt) {
          const float pp = exp2_hw(sv[nt] - mcur);
          rsum += pp;
          Ps[(wrow + mt * 16 + lq * 4 + i) * 64 + ((nt * 16 + lc) ^ psw)] =
              __float2bfloat16(pp);
        }
        l_st[mt][i] += rsum;   // per-lane partial; reduced once at the end
      }
    }
    // no barrier: Ps rows written/read by the same wave only

    __builtin_amdgcn_s_setprio(1);
#pragma unroll
    for (int ks = 0; ks < 2; ++ks) {
      bf16x8 pa[2];
#pragma unroll
      for (int mt = 0; mt < 2; ++mt)
        pa[mt] = *reinterpret_cast<const bf16x8*>(
            &Ps[(wrow + mt * 16 + lc) * 64 +
                ((ks * 32 + lq * 8) ^ ((lc & 7) << 3))]);
#pragma unroll
      for (int nt = 0; nt < 8; ++nt) {
        const bf16x8 vb = *reinterpret_cast<const bf16x8*>(
            &Vs[cur][(nt * 16 + lc) * 64 +
                     ((ks * 32 + lq * 8) ^ ((lc & 7) << 3))]);
#pragma unroll
        for (int mt = 0; mt < 2; ++mt)
          o_acc[mt][nt] = mfma16x16(pa[mt], vb, o_acc[mt][nt]);
      }
    }
    __builtin_amdgcn_s_setprio(0);
    GBAR();   // this tile's reads done before next tile's DMA into buf^1
  }

  // write attention output into the Q region of qkv
#pragma unroll
  for (int mt = 0; mt < 2; ++mt)
#pragma unroll
    for (int i = 0; i < 4; ++i) {
      float l = l_st[mt][i];
#pragma unroll
      for (int off = 1; off < 16; off <<= 1) l += __shfl_xor(l, off, 64);
      const float inv_l = 1.0f / l;
      bf16_t* op =
          qkv + (long)(b * S_ + qt * 256 + wrow + mt * 16 + lq * 4 + i) * QKVN_ +
          h * HD_ + lc;
#pragma unroll
      for (int nt = 0; nt < 8; ++nt)
        op[nt * 16] = __float2bfloat16(o_acc[mt][nt][i] * inv_l);
    }
}

// ---------------------------------------------------------------------------
extern "C" void kernel_launch(void* const* d_in, const int* in_sizes, int n_in,
                              void* d_out, int out_size, void* d_ws,
                              size_t ws_size, hipStream_t stream) {
  const int* pos = (const int*)d_in[3];

  char* ws = (char*)d_ws;
  bf16_t* qkv  = (bf16_t*)ws;                                   // 100.66 MB
  const size_t QKV_B = (size_t)MTOK_ * QKVN_ * 2;
  int*    flag = (int*)(ws + QKV_B);
  bf16_t* vt   = (bf16_t*)d_out;  // scratch before final out is written

  // tiered bf16 conversion scratch (enables global_load_lds in the GEMMs)
  const size_t off  = QKV_B + 512;
  const size_t WP_B = (size_t)QKVN_ * H_ * 2;   // 100.66 MB
  const size_t WO_B = (size_t)H_ * H_ * 2;      //  33.55 MB
  const size_t A_B  = (size_t)MTOK_ * H_ * 2;   //  33.55 MB
  const bool cvtWP = ws_size >= off + WP_B;
  const bool cvtWO = ws_size >= off + WP_B + WO_B;
  const bool cvtA  = ws_size >= off + WP_B + WO_B + A_B;
  bf16_t* wpb = (bf16_t*)(ws + off);
  bf16_t* wob = (bf16_t*)(ws + off + WP_B);
  bf16_t* abf = (bf16_t*)(ws + off + WP_B + WO_B);

  bh_detect<<<dim3(1), dim3(256), 0, stream>>>(
      (const unsigned short*)d_in[1], flag);

  if (cvtWP)
    bh_convert<<<dim3(2048), dim3(256), 0, stream>>>(
        d_in[1], wpb, (long)QKVN_ * H_ / 8, flag);
  if (cvtWO)
    bh_convert<<<dim3(2048), dim3(256), 0, stream>>>(
        d_in[2], wob, (long)H_ * H_ / 8, flag);
  if (cvtA)
    bh_convert<<<dim3(2048), dim3(256), 0, stream>>>(
        d_in[0], abf, (long)MTOK_ * H_ / 8, flag);

  if (cvtA)
    bh_gemm2<0><<<dim3(QKVN_ / 256, MTOK_ / 256), dim3(512), 0, stream>>>(
        abf, H_, wpb, H_, qkv, QKVN_, H_, flag);
  else if (cvtWP)
    bh_gemm<1, 0, 0><<<dim3(QKVN_ / 128, MTOK_ / 128), dim3(256), 0, stream>>>(
        d_in[0], H_, wpb, H_, qkv, QKVN_, QKVN_, H_, flag);
  else
    bh_gemm<1, 1, 0><<<dim3(QKVN_ / 128, MTOK_ / 128), dim3(256), 0, stream>>>(
        d_in[0], H_, d_in[1], H_, qkv, QKVN_, QKVN_, H_, flag);

  bh_rope<<<dim3((MTOK_ * NH_ * 64) / 256), dim3(256), 0, stream>>>(qkv, pos);
  bh_transpose_v<<<dim3(S_ / 64, NH_, B_), dim3(256), 0, stream>>>(qkv, vt);
  bh_flash<<<dim3((S_ / 256) * NH_ * B_), dim3(512), 0, stream>>>(qkv, vt);

  if (cvtWO)
    bh_gemm2<1><<<dim3(H_ / 256, MTOK_ / 256), dim3(512), 0, stream>>>(
        qkv, QKVN_, wob, H_, d_out, H_, H_, flag);
  else
    bh_gemm<0, 1, 1><<<dim3(H_ / 128, MTOK_ / 128), dim3(256), 0, stream>>>(
        qkv, QKVN_, d_in[2], H_, d_out, H_, H_, H_, flag);
}

// Round 6
// 1139.722 us; speedup vs baseline: 1.0433x; 1.0055x over previous
//
#include <hip/hip_runtime.h>
#include <hip/hip_bf16.h>
#include <math.h>

#define B_    2
#define S_    2048
#define H_    4096
#define NH_   32
#define HD_   128
#define MTOK_ (B_ * S_)     // 4096 tokens
#define QKVN_ (3 * H_)      // 12288

using bf16_t = __hip_bfloat16;
typedef __bf16 bf16x8 __attribute__((ext_vector_type(8)));
typedef unsigned short u16x8 __attribute__((ext_vector_type(8)));
typedef float f32x4 __attribute__((ext_vector_type(4)));

// async global->LDS, 16B per lane; LDS base must be wave-uniform
// (HW writes lane i at base + i*16B).
#define ASYNC_COPY16(g, l)                                                     \
  __builtin_amdgcn_global_load_lds(                                            \
      (__attribute__((address_space(1))) void*)(g),                            \
      (__attribute__((address_space(3))) void*)(l), 16, 0, 0)

static __device__ __forceinline__ f32x4 mfma16x16(bf16x8 a, bf16x8 b, f32x4 c) {
  return __builtin_amdgcn_mfma_f32_16x16x32_bf16(a, b, c, 0, 0, 0);
}

static __device__ __forceinline__ float bits_to_f(unsigned short v) {
  union { unsigned int u; float f; } cv;
  cv.u = ((unsigned int)v) << 16;
  return cv.f;
}

// raw v_exp_f32 (2^x). Non-volatile: pure, lets the scheduler place it.
static __device__ __forceinline__ float exp2_hw(float x) {
  float r;
  asm("v_exp_f32 %0, %1" : "=v"(r) : "v"(x));
  return r;
}

#define GBAR()                                                                 \
  do {                                                                         \
    __builtin_amdgcn_s_barrier();                                              \
    __builtin_amdgcn_sched_barrier(0);                                         \
  } while (0)

#define LGKM0()                                                                \
  do {                                                                         \
    asm volatile("s_waitcnt lgkmcnt(0)" ::: "memory");                         \
    __builtin_amdgcn_sched_barrier(0);                                         \
  } while (0)

// ---------------------------------------------------------------------------
// dtype probe: if the float inputs are fp32, random mantissa halves decode to
// huge bf16 values; if genuine bf16 (|x|<~0.2 here), all 64K u16s stay small.
// ---------------------------------------------------------------------------
__global__ void bh_detect(const unsigned short* __restrict__ p,
                          int* __restrict__ flag) {
  __shared__ float red[4];
  float m = 0.f;
  const int tid = threadIdx.x;
  for (int i = tid; i < 65536; i += 256) {
    const float f = fabsf(bits_to_f(p[i]));
    m = fmaxf(m, f);  // fmaxf(m, NaN) == m
  }
  for (int off = 1; off < 64; off <<= 1) m = fmaxf(m, __shfl_xor(m, off, 64));
  if ((tid & 63) == 0) red[tid >> 6] = m;
  __syncthreads();
  if (tid == 0) {
    const float mm = fmaxf(fmaxf(red[0], red[1]), fmaxf(red[2], red[3]));
    *flag = (mm > 1.0f) ? 1 : 0;  // 1 => inputs/outputs are fp32
  }
}

// ---------------------------------------------------------------------------
// one-shot dtype normalization: fp32 -> bf16 convert (or bf16 copy), so the
// GEMMs can always use the global_load_lds (async 16B) staging path.
// ---------------------------------------------------------------------------
__global__ __launch_bounds__(256)
void bh_convert(const void* __restrict__ src, bf16_t* __restrict__ dst,
                long n8, const int* __restrict__ flag) {
  const int isf = *flag;
  const long stride = (long)gridDim.x * 256;
  long i = (long)blockIdx.x * 256 + threadIdx.x;
  if (isf) {
    const f32x4* s = (const f32x4*)src;
    for (; i < n8; i += stride) {
      const f32x4 f0 = s[2 * i];
      const f32x4 f1 = s[2 * i + 1];
      bf16x8 o;
      o[0] = (__bf16)f0[0]; o[1] = (__bf16)f0[1];
      o[2] = (__bf16)f0[2]; o[3] = (__bf16)f0[3];
      o[4] = (__bf16)f1[0]; o[5] = (__bf16)f1[1];
      o[6] = (__bf16)f1[2]; o[7] = (__bf16)f1[3];
      *reinterpret_cast<bf16x8*>(dst + i * 8) = o;
    }
  } else {
    const u16x8* s = (const u16x8*)src;
    for (; i < n8; i += stride)
      reinterpret_cast<u16x8*>(dst)[i] = s[i];
  }
}

// fp32 staging: read 8 floats, convert, one ds_write_b128 (same LDS layout
// the async path produces).
static __device__ __forceinline__ void stage32(const float* __restrict__ g,
                                               bf16_t* __restrict__ l) {
  const f32x4 f0 = *reinterpret_cast<const f32x4*>(g);
  const f32x4 f1 = *reinterpret_cast<const f32x4*>(g + 4);
  bf16x8 o;
  o[0] = (__bf16)f0[0]; o[1] = (__bf16)f0[1];
  o[2] = (__bf16)f0[2]; o[3] = (__bf16)f0[3];
  o[4] = (__bf16)f1[0]; o[5] = (__bf16)f1[1];
  o[6] = (__bf16)f1[2]; o[7] = (__bf16)f1[3];
  *reinterpret_cast<bf16x8*>(l) = o;
}

// ---------------------------------------------------------------------------
// Fallback NT GEMM (128x128 tile, 2-barrier loop) for when the workspace is
// too small to pre-convert operands. Unchanged from the verified version.
// ---------------------------------------------------------------------------
template <int AMODE, int BMODE, int CMODE>
__global__ __launch_bounds__(256, 2)
void bh_gemm(const void* __restrict__ Ap, int lda,
             const void* __restrict__ Bp, int ldb,
             void* __restrict__ Cp, int ldc, int N, int K,
             const int* __restrict__ flag) {
  __shared__ bf16_t As[128 * 32];
  __shared__ bf16_t Bs[128 * 32];
  const int isf = *flag;
  const bool a_f32 = AMODE && isf;
  const bool b_f32 = BMODE && isf;

  const int tid = threadIdx.x, wave = tid >> 6, lane = tid & 63;
  const int lq = lane >> 4, lc = lane & 15;
  const int m0 = blockIdx.y * 128, n0 = blockIdx.x * 128;
  const int wm = (wave >> 1) * 64, wn = (wave & 1) * 64;

  f32x4 acc[4][4] = {};

  const int srow  = wave * 16 + (lane >> 2);
  const int skoff = (lane & 3) * 8;

  const bf16_t* a16 = (const bf16_t*)Ap;
  const float*  a32 = (const float*)Ap;
  const bf16_t* b16 = (const bf16_t*)Bp;
  const float*  b32 = (const float*)Bp;

  bf16_t* lA0u = As + wave * 512;
  bf16_t* lA1u = As + 2048 + wave * 512;
  bf16_t* lB0u = Bs + wave * 512;
  bf16_t* lB1u = Bs + 2048 + wave * 512;
  bf16_t* lA0p = lA0u + lane * 8;
  bf16_t* lA1p = lA1u + lane * 8;
  bf16_t* lB0p = lB0u + lane * 8;
  bf16_t* lB1p = lB1u + lane * 8;

  const int aoff = (wm + lc) * 32 + lq * 8;
  const int boff = (wn + lc) * 32 + lq * 8;

  for (int k = 0; k < K; k += 32) {
    if (a_f32) {
      stage32(a32 + (long)(m0 + srow) * lda + skoff + k, lA0p);
      stage32(a32 + (long)(m0 + srow + 64) * lda + skoff + k, lA1p);
    } else {
      ASYNC_COPY16(a16 + (long)(m0 + srow) * lda + skoff + k, lA0u);
      ASYNC_COPY16(a16 + (long)(m0 + srow + 64) * lda + skoff + k, lA1u);
    }
    if (b_f32) {
      stage32(b32 + (long)(n0 + srow) * ldb + skoff + k, lB0p);
      stage32(b32 + (long)(n0 + srow + 64) * ldb + skoff + k, lB1p);
    } else {
      ASYNC_COPY16(b16 + (long)(n0 + srow) * ldb + skoff + k, lB0u);
      ASYNC_COPY16(b16 + (long)(n0 + srow + 64) * ldb + skoff + k, lB1u);
    }
    __syncthreads();
    bf16x8 af[4], bfr[4];
#pragma unroll
    for (int i = 0; i < 4; ++i) {
      af[i]  = *reinterpret_cast<const bf16x8*>(&As[aoff + i * 512]);
      bfr[i] = *reinterpret_cast<const bf16x8*>(&Bs[boff + i * 512]);
    }
#pragma unroll
    for (int mi = 0; mi < 4; ++mi)
#pragma unroll
      for (int ni = 0; ni < 4; ++ni)
        acc[mi][ni] = mfma16x16(af[mi], bfr[ni], acc[mi][ni]);
    __syncthreads();
  }

  const bool c_f32 = CMODE && isf;
#pragma unroll
  for (int mi = 0; mi < 4; ++mi)
#pragma unroll
    for (int ni = 0; ni < 4; ++ni)
#pragma unroll
      for (int i = 0; i < 4; ++i) {
        const long row = m0 + wm + mi * 16 + lq * 4 + i;
        const long col = n0 + wn + ni * 16 + lc;
        const float v = acc[mi][ni][i];
        if (c_f32)
          ((float*)Cp)[row * ldc + col] = v;
        else
          ((bf16_t*)Cp)[row * ldc + col] = __float2bfloat16(v);
      }
}

// ---------------------------------------------------------------------------
// 256x256 8-phase bf16 NT GEMM (m201-style). BK=64, 8 waves, counted
// vmcnt(6), LDS XOR-swizzle chunk^=row&7 via pre-swizzled global source.
// NO XCD swizzle: operands are L3-fit here (134 MB); R4's A/B showed the
// chunked swizzle desynchronizes the XCD sweeps over B -> FETCH 295->825 MB.
// ---------------------------------------------------------------------------
template <int CMODE>
__global__ __launch_bounds__(512, 2)
void bh_gemm2(const bf16_t* __restrict__ Ap, int lda,
              const bf16_t* __restrict__ Bp, int ldb,
              void* __restrict__ Cp, int ldc, int K,
              const int* __restrict__ flag) {
  __shared__ bf16_t As[2][2][128 * 64];
  __shared__ bf16_t Bs[2][2][128 * 64];
  const int isf = *flag;

  const int tid = threadIdx.x, wave = tid >> 6, lane = tid & 63;
  const int lq = lane >> 4, lc = lane & 15;
  const int wm2 = wave >> 2;
  const int wn4 = wave & 3;
  const int m0 = blockIdx.y * 256, n0 = blockIdx.x * 256;
  const int NT = K >> 6;

  const int srow = wave * 16 + (lane >> 3);
  const int gcol = ((lane & 7) ^ (lane >> 3)) * 8;
  const int lbase = wave * 1024;

  f32x4 acc[8][4] = {};
  bf16x8 aA[2][4];
  bf16x8 bB[2][2][2];

  auto stageA = [&](int tau, int h) {
    if (tau >= NT) return;
    const bf16_t* g = Ap + (long)(m0 + h * 128 + srow) * lda + tau * 64 + gcol;
    bf16_t* l = &As[tau & 1][h][lbase];
    ASYNC_COPY16(g, l);
    ASYNC_COPY16(g + (long)8 * lda, l + 512);
  };
  auto stageB = [&](int tau, int h) {
    if (tau >= NT) return;
    const bf16_t* g = Bp + (long)(n0 + h * 128 + srow) * ldb + tau * 64 + gcol;
    bf16_t* l = &Bs[tau & 1][h][lbase];
    ASYNC_COPY16(g, l);
    ASYNC_COPY16(g + (long)8 * ldb, l + 512);
  };
  auto ldA = [&](int buf, int h) {
#pragma unroll
    for (int ks = 0; ks < 2; ++ks)
#pragma unroll
      for (int f = 0; f < 4; ++f) {
        const int row = wm2 * 64 + f * 16 + lc;
        aA[ks][f] = *reinterpret_cast<const bf16x8*>(
            &As[buf][h][row * 64 + (((ks * 4 + lq) ^ (row & 7)) * 8)]);
      }
  };
  auto ldB = [&](int buf, int h, bf16x8 (&dst)[2][2]) {
#pragma unroll
    for (int ks = 0; ks < 2; ++ks)
#pragma unroll
      for (int g = 0; g < 2; ++g) {
        const int row = wn4 * 32 + g * 16 + lc;
        dst[ks][g] = *reinterpret_cast<const bf16x8*>(
            &Bs[buf][h][row * 64 + (((ks * 4 + lq) ^ (row & 7)) * 8)]);
      }
  };

#define MMA_QUAD(qm, qn)                                                       \
  do {                                                                         \
    __builtin_amdgcn_s_setprio(1);                                             \
    _Pragma("unroll") for (int f = 0; f < 4; ++f) {                            \
      _Pragma("unroll") for (int g = 0; g < 2; ++g) {                          \
        f32x4 c = acc[(qm) * 4 + f][(qn) * 2 + g];                             \
        c = mfma16x16(aA[0][f], bB[qn][0][g], c);                              \
        c = mfma16x16(aA[1][f], bB[qn][1][g], c);                              \
        acc[(qm) * 4 + f][(qn) * 2 + g] = c;                                   \
      }                                                                        \
    }                                                                          \
    __builtin_amdgcn_s_setprio(0);                                             \
  } while (0)

  stageA(0, 0); stageB(0, 0); stageB(0, 1); stageA(0, 1);
  stageA(1, 0); stageB(1, 0); stageB(1, 1);
  asm volatile("s_waitcnt vmcnt(6)" ::: "memory");
  GBAR();

  for (int T = 0; T < NT; ++T) {
    const int buf = T & 1;
    ldA(buf, 0);
    ldB(buf, 0, bB[0]);
    stageA(T + 1, 1);
    asm volatile("s_waitcnt lgkmcnt(8)" ::: "memory");
    GBAR();
    LGKM0();
    MMA_QUAD(0, 0);
    GBAR();
    ldB(buf, 1, bB[1]);
    stageA(T + 2, 0);
    GBAR();
    LGKM0();
    MMA_QUAD(0, 1);
    GBAR();
    ldA(buf, 1);
    stageB(T + 2, 0);
    GBAR();
    LGKM0();
    MMA_QUAD(1, 1);
    GBAR();
    stageB(T + 2, 1);
    if (T + 2 < NT)
      asm volatile("s_waitcnt vmcnt(6)" ::: "memory");
    else
      asm volatile("s_waitcnt vmcnt(0)" ::: "memory");
    GBAR();
    MMA_QUAD(1, 0);
    GBAR();
  }

  const bool c_f32 = CMODE && isf;
#pragma unroll
  for (int mi = 0; mi < 8; ++mi)
#pragma unroll
    for (int ni = 0; ni < 4; ++ni)
#pragma unroll
      for (int i = 0; i < 4; ++i) {
        const long row =
            m0 + (mi >> 2) * 128 + wm2 * 64 + (mi & 3) * 16 + lq * 4 + i;
        const long col =
            n0 + (ni >> 1) * 128 + wn4 * 32 + (ni & 1) * 16 + lc;
        const float v = acc[mi][ni][i];
        if (c_f32)
          ((float*)Cp)[row * ldc + col] = v;
        else
          ((bf16_t*)Cp)[row * ldc + col] = __float2bfloat16(v);
      }
}

// ---------------------------------------------------------------------------
// RoPE table: tab[m*64+d] = {cos, sin}(pos[m] * 10000^(-d/64)). One-shot
// (262k threads) hoists ALL transcendentals out of the hot rope pass --
// the old in-loop powf+sincosf over 8.4M threads was ~300-500 us of pure
// serial VALU (Appendix-B trap: trig turns memory-bound RoPE VALU-bound).
// ---------------------------------------------------------------------------
__global__ __launch_bounds__(256)
void bh_mktab(const int* __restrict__ pos, float2* __restrict__ tab) {
  const int idx = blockIdx.x * 256 + threadIdx.x;  // m*64 + d
  if (idx >= MTOK_ * 64) return;
  const int d = idx & 63, m = idx >> 6;
  const float p = (float)pos[m];
  const float inv_freq = exp2f((float)d * -0.20762050593046777f);  // log2(1e4)/64
  float sn, cs;
  sincosf(p * inv_freq, &sn, &cs);
  tab[idx] = make_float2(cs, sn);
}

// RoPE (neox half-split) in-place on Q and K regions of qkv, table-driven:
// pure memory op (~270 MB of qkv traffic + 67 MB table reads).
__global__ void bh_rope2(bf16_t* __restrict__ qkv,
                         const float2* __restrict__ tab) {
  const int idx = blockIdx.x * 256 + threadIdx.x;
  const int d = idx & 63;
  const int h = (idx >> 6) & (NH_ - 1);
  const int m = idx >> 11;
  if (m >= MTOK_) return;
  const float2 t = tab[(m << 6) + d];
  const float cs = t.x, sn = t.y;
  bf16_t* q  = qkv + (long)m * QKVN_ + h * HD_;
  bf16_t* kk = q + H_;
  const float q1 = __bfloat162float(q[d]);
  const float q2 = __bfloat162float(q[d + 64]);
  q[d]      = __float2bfloat16(q1 * cs - q2 * sn);
  q[d + 64] = __float2bfloat16(q2 * cs + q1 * sn);
  const float k1 = __bfloat162float(kk[d]);
  const float k2 = __bfloat162float(kk[d + 64]);
  kk[d]      = __float2bfloat16(k1 * cs - k2 * sn);
  kk[d + 64] = __float2bfloat16(k2 * cs + k1 * sn);
}

// Fallback trig RoPE (used only if the workspace can't hold the table).
__global__ void bh_rope(bf16_t* __restrict__ qkv, const int* __restrict__ pos) {
  const int idx = blockIdx.x * 256 + threadIdx.x;
  const int d = idx & 63;
  const int h = (idx >> 6) & (NH_ - 1);
  const int m = idx >> 11;
  if (m >= MTOK_) return;
  const float p = (float)pos[m];
  const float inv_freq = 1.0f / powf(10000.0f, (float)d * (1.0f / 64.0f));
  float sn, cs;
  sincosf(p * inv_freq, &sn, &cs);
  bf16_t* q  = qkv + (long)m * QKVN_ + h * HD_;
  bf16_t* kk = q + H_;
  const float q1 = __bfloat162float(q[d]);
  const float q2 = __bfloat162float(q[d + 64]);
  q[d]      = __float2bfloat16(q1 * cs - q2 * sn);
  q[d + 64] = __float2bfloat16(q2 * cs + q1 * sn);
  const float k1 = __bfloat162float(kk[d]);
  const float k2 = __bfloat162float(kk[d + 64]);
  kk[d]      = __float2bfloat16(k1 * cs - k2 * sn);
  kk[d + 64] = __float2bfloat16(k2 * cs + k1 * sn);
}

// ---------------------------------------------------------------------------
// V transpose: qkv V region [token][h*128+d] -> vt[b][h][d][token]
// ---------------------------------------------------------------------------
__global__ void bh_transpose_v(const bf16_t* __restrict__ qkv,
                               bf16_t* __restrict__ vt) {
  __shared__ unsigned short tile[128][65];
  const int t0 = blockIdx.x * 64;
  const int h  = blockIdx.y;
  const int b  = blockIdx.z;
  const int tid = threadIdx.x;
#pragma unroll
  for (int pass = 0; pass < 4; ++pass) {
    const int row = (tid >> 4) + pass * 16;
    const int dc  = (tid & 15) * 8;
    const u16x8 v = *reinterpret_cast<const u16x8*>(
        qkv + (long)(b * S_ + t0 + row) * QKVN_ + 2 * H_ + h * HD_ + dc);
#pragma unroll
    for (int j = 0; j < 8; ++j) tile[dc + j][row] = v[j];
  }
  __syncthreads();
#pragma unroll
  for (int pass = 0; pass < 4; ++pass) {
    const int d  = (tid >> 3) + pass * 32;
    const int tc = (tid & 7) * 8;
    u16x8 o;
#pragma unroll
    for (int j = 0; j < 8; ++j) o[j] = tile[d][tc + j];
    *reinterpret_cast<u16x8*>(
        vt + ((long)(b * NH_ + h) * HD_ + d) * S_ + t0 + tc) = o;
  }
}

// ---------------------------------------------------------------------------
// Causal flash attention, 256 Q-rows / 8 waves per block, double-buffered K/V
// with counted per-wave vmcnt(4). Softmax in log2 domain, T13 defer-max,
// per-lane partial l reduced once at the end. Sync structure: stage(t+1,buf^1)
// | vmcnt(4) | s_barrier | QK^T | softmax (Ps wave-private) | PV | s_barrier.
// Grid 1D longest-first. LDS XOR-swizzled (chunk ^= row&7, 16B units).
// ---------------------------------------------------------------------------
__global__ __launch_bounds__(512)
void bh_flash(bf16_t* __restrict__ qkv, const bf16_t* __restrict__ vt) {
  __shared__ bf16_t Ks[2][64 * 128];   // [token][dim], dim-chunk ^= token&7
  __shared__ bf16_t Vs[2][128 * 64];   // [dim][token], token-chunk ^= dim&7
  __shared__ bf16_t Ps[256 * 64];      // [qrow][token], token-chunk ^= qrow&7
  const int idx = blockIdx.x;
  const int qt = (S_ / 256 - 1) - (idx >> 6);  // longest-first: 7..0
  const int bh = idx & 63;
  const int b  = bh >> 5;
  const int h  = bh & (NH_ - 1);
  const int tid = threadIdx.x, wave = tid >> 6, lane = tid & 63;
  const int lq = lane >> 4, lc = lane & 15;
  const int wrow = wave * 32;
  const float scale2 = 0.12751744f;  // log2(e) / sqrt(128)

  bf16x8 qf[2][4];
#pragma unroll
  for (int mt = 0; mt < 2; ++mt) {
    const bf16_t* qp =
        qkv + (long)(b * S_ + qt * 256 + wrow + mt * 16 + lc) * QKVN_ +
        h * HD_ + lq * 8;
#pragma unroll
    for (int ks = 0; ks < 4; ++ks)
      qf[mt][ks] = *reinterpret_cast<const bf16x8*>(qp + ks * 32);
  }

  f32x4 o_acc[2][8] = {};
  float m_st[2][4], l_st[2][4];
#pragma unroll
  for (int mt = 0; mt < 2; ++mt)
#pragma unroll
    for (int i = 0; i < 4; ++i) { m_st[mt][i] = -1e30f; l_st[mt][i] = 0.f; }

  // stage K/V tile kt into buffer bsel (4 async copies per wave, 8 waves)
  auto stage = [&](int kt, int bsel) {
    const int t0 = kt * 64;
#pragma unroll
    for (int j = 0; j < 2; ++j) {
      const int p = wave * 2 + j;
      const int trow = p * 4 + (lane >> 4);
      const int kcs  = ((lane & 15) ^ (trow & 7)) * 8;
      ASYNC_COPY16(qkv + (long)(b * S_ + t0 + trow) * QKVN_ + H_ + h * HD_ + kcs,
                   &Ks[bsel][p * 512]);
      const int vrow = p * 8 + (lane >> 3);
      const int tcs  = ((lane & 7) ^ (lane >> 3)) * 8;   // vrow&7 == lane>>3
      ASYNC_COPY16(vt + ((long)(b * NH_ + h) * HD_ + vrow) * S_ + t0 + tcs,
                   &Vs[bsel][p * 512]);
    }
  };

  const int ktiles = 4 * qt + 4;
  stage(0, 0);

  for (int kt = 0; kt < ktiles; ++kt) {
    const int cur = kt & 1;
    if (kt + 1 < ktiles) {
      stage(kt + 1, cur ^ 1);
      asm volatile("s_waitcnt vmcnt(4)" ::: "memory");
    } else {
      asm volatile("s_waitcnt vmcnt(0)" ::: "memory");
    }
    GBAR();

    const int t0 = kt * 64;
    f32x4 sa[2][4] = {};
    __builtin_amdgcn_s_setprio(1);
#pragma unroll
    for (int ks = 0; ks < 4; ++ks) {
      bf16x8 bb[4];
#pragma unroll
      for (int nt = 0; nt < 4; ++nt)
        bb[nt] = *reinterpret_cast<const bf16x8*>(
            &Ks[cur][(nt * 16 + lc) * 128 +
                     ((ks * 32 + lq * 8) ^ ((lc & 7) << 3))]);
#pragma unroll
      for (int mt = 0; mt < 2; ++mt)
#pragma unroll
        for (int nt = 0; nt < 4; ++nt)
          sa[mt][nt] = mfma16x16(qf[mt][ks], bb[nt], sa[mt][nt]);
    }
    __builtin_amdgcn_s_setprio(0);

#pragma unroll
    for (int mt = 0; mt < 2; ++mt) {
#pragma unroll
      for (int i = 0; i < 4; ++i) {
        const int qg = qt * 256 + wrow + mt * 16 + lq * 4 + i;
        float sv[4];
        float mloc = -1e30f;
#pragma unroll
        for (int nt = 0; nt < 4; ++nt) {
          float v = sa[mt][nt][i] * scale2;
          if (t0 + nt * 16 + lc > qg) v = -1e30f;
          sv[nt] = v;
          mloc = fmaxf(mloc, v);
        }
#pragma unroll
        for (int off = 1; off < 16; off <<= 1)
          mloc = fmaxf(mloc, __shfl_xor(mloc, off, 64));
        // T13 defer-max: rescale only when the row max grew > 8 (log2 units).
        if (!__all(mloc - m_st[mt][i] <= 8.0f)) {
          const float mnew = fmaxf(m_st[mt][i], mloc);
          const float alpha = exp2_hw(m_st[mt][i] - mnew);
          l_st[mt][i] *= alpha;
#pragma unroll
          for (int nt = 0; nt < 8; ++nt) o_acc[mt][nt][i] *= alpha;
          m_st[mt][i] = mnew;
        }
        const float mcur = m_st[mt][i];
        float rsum = 0.f;
        const int psw = ((lq * 4 + i) & 7) << 3;   // row&7 of the Ps row
#pragma unroll
        for (int nt = 0; nt < 4; ++nt) {
          const float pp = exp2_hw(sv[nt] - mcur);
          rsum += pp;
          Ps[(wrow + mt * 16 + lq * 4 + i) * 64 + ((nt * 16 + lc) ^ psw)] =
              __float2bfloat16(pp);
        }
        l_st[mt][i] += rsum;   // per-lane partial; reduced once at the end
      }
    }
    // no barrier: Ps rows written/read by the same wave only

    __builtin_amdgcn_s_setprio(1);
#pragma unroll
    for (int ks = 0; ks < 2; ++ks) {
      bf16x8 pa[2];
#pragma unroll
      for (int mt = 0; mt < 2; ++mt)
        pa[mt] = *reinterpret_cast<const bf16x8*>(
            &Ps[(wrow + mt * 16 + lc) * 64 +
                ((ks * 32 + lq * 8) ^ ((lc & 7) << 3))]);
#pragma unroll
      for (int nt = 0; nt < 8; ++nt) {
        const bf16x8 vb = *reinterpret_cast<const bf16x8*>(
            &Vs[cur][(nt * 16 + lc) * 64 +
                     ((ks * 32 + lq * 8) ^ ((lc & 7) << 3))]);
#pragma unroll
        for (int mt = 0; mt < 2; ++mt)
          o_acc[mt][nt] = mfma16x16(pa[mt], vb, o_acc[mt][nt]);
      }
    }
    __builtin_amdgcn_s_setprio(0);
    GBAR();   // this tile's reads done before next tile's DMA into buf^1
  }

  // write attention output into the Q region of qkv
#pragma unroll
  for (int mt = 0; mt < 2; ++mt)
#pragma unroll
    for (int i = 0; i < 4; ++i) {
      float l = l_st[mt][i];
#pragma unroll
      for (int off = 1; off < 16; off <<= 1) l += __shfl_xor(l, off, 64);
      const float inv_l = 1.0f / l;
      bf16_t* op =
          qkv + (long)(b * S_ + qt * 256 + wrow + mt * 16 + lq * 4 + i) * QKVN_ +
          h * HD_ + lc;
#pragma unroll
      for (int nt = 0; nt < 8; ++nt)
        op[nt * 16] = __float2bfloat16(o_acc[mt][nt][i] * inv_l);
    }
}

// ---------------------------------------------------------------------------
extern "C" void kernel_launch(void* const* d_in, const int* in_sizes, int n_in,
                              void* d_out, int out_size, void* d_ws,
                              size_t ws_size, hipStream_t stream) {
  const int* pos = (const int*)d_in[3];

  char* ws = (char*)d_ws;
  bf16_t* qkv  = (bf16_t*)ws;                                   // 100.66 MB
  const size_t QKV_B = (size_t)MTOK_ * QKVN_ * 2;
  int*    flag = (int*)(ws + QKV_B);
  bf16_t* vt   = (bf16_t*)d_out;  // scratch before final out is written

  // tiered bf16 conversion scratch (enables global_load_lds in the GEMMs)
  const size_t off  = QKV_B + 512;
  const size_t WP_B = (size_t)QKVN_ * H_ * 2;   // 100.66 MB
  const size_t WO_B = (size_t)H_ * H_ * 2;      //  33.55 MB
  const size_t A_B  = (size_t)MTOK_ * H_ * 2;   //  33.55 MB
  const size_t TAB_B = (size_t)MTOK_ * 64 * 8;  //   2.10 MB (RoPE cos/sin)
  const bool cvtWP = ws_size >= off + WP_B;
  const bool cvtWO = ws_size >= off + WP_B + WO_B;
  const bool cvtA  = ws_size >= off + WP_B + WO_B + A_B;
  const bool hasTab = ws_size >= off + WP_B + WO_B + A_B + TAB_B;
  bf16_t* wpb = (bf16_t*)(ws + off);
  bf16_t* wob = (bf16_t*)(ws + off + WP_B);
  bf16_t* abf = (bf16_t*)(ws + off + WP_B + WO_B);
  float2* tab = (float2*)(ws + off + WP_B + WO_B + A_B);

  bh_detect<<<dim3(1), dim3(256), 0, stream>>>(
      (const unsigned short*)d_in[1], flag);

  if (hasTab)
    bh_mktab<<<dim3((MTOK_ * 64) / 256), dim3(256), 0, stream>>>(pos, tab);

  if (cvtWP)
    bh_convert<<<dim3(2048), dim3(256), 0, stream>>>(
        d_in[1], wpb, (long)QKVN_ * H_ / 8, flag);
  if (cvtWO)
    bh_convert<<<dim3(2048), dim3(256), 0, stream>>>(
        d_in[2], wob, (long)H_ * H_ / 8, flag);
  if (cvtA)
    bh_convert<<<dim3(2048), dim3(256), 0, stream>>>(
        d_in[0], abf, (long)MTOK_ * H_ / 8, flag);

  if (cvtA)
    bh_gemm2<0><<<dim3(QKVN_ / 256, MTOK_ / 256), dim3(512), 0, stream>>>(
        abf, H_, wpb, H_, qkv, QKVN_, H_, flag);
  else if (cvtWP)
    bh_gemm<1, 0, 0><<<dim3(QKVN_ / 128, MTOK_ / 128), dim3(256), 0, stream>>>(
        d_in[0], H_, wpb, H_, qkv, QKVN_, QKVN_, H_, flag);
  else
    bh_gemm<1, 1, 0><<<dim3(QKVN_ / 128, MTOK_ / 128), dim3(256), 0, stream>>>(
        d_in[0], H_, d_in[1], H_, qkv, QKVN_, QKVN_, H_, flag);

  if (hasTab)
    bh_rope2<<<dim3((MTOK_ * NH_ * 64) / 256), dim3(256), 0, stream>>>(qkv, tab);
  else
    bh_rope<<<dim3((MTOK_ * NH_ * 64) / 256), dim3(256), 0, stream>>>(qkv, pos);

  bh_transpose_v<<<dim3(S_ / 64, NH_, B_), dim3(256), 0, stream>>>(qkv, vt);
  bh_flash<<<dim3((S_ / 256) * NH_ * B_), dim3(512), 0, stream>>>(qkv, vt);

  if (cvtWO)
    bh_gemm2<1><<<dim3(H_ / 256, MTOK_ / 256), dim3(512), 0, stream>>>(
        qkv, QKVN_, wob, H_, d_out, H_, H_, flag);
  else
    bh_gemm<0, 1, 1><<<dim3(H_ / 128, MTOK_ / 128), dim3(256), 0, stream>>>(
        qkv, QKVN_, d_in[2], H_, d_out, H_, H_, H_, flag);
}